// Round 1
// baseline (6256.318 us; speedup 1.0000x reference)
//
#include <hip/hip_runtime.h>
#include <math.h>

#define Bsz 1024
#define Lsz 50
#define Esz 256
#define Hsz 256
#define NEGV (-1e9f)

// ============================================================
// init: copy decoder_input -> dec buffer, zero the mask
// grid: 1024 x 256 == B*E threads
// ============================================================
__global__ void init_kernel(const float* __restrict__ dec0,
                            float* __restrict__ dec,
                            int* __restrict__ mask)
{
    int i = blockIdx.x * 256 + threadIdx.x;
    dec[i] = dec0[i];                 // exactly B*E threads
    if (i < Bsz * Lsz) mask[i] = 0;
}

// ============================================================
// e-projection GEMM: Eo[b,l,h] = sum_k context[l,b,k]*W[h,k] + bias[h]
// context flattened as A[(l*B+b), k].  64x64 tiles, 256 threads, 4x4 micro.
// grid: (L*B/64, H/64)
// ============================================================
__global__ __launch_bounds__(256) void eproj_kernel(const float* __restrict__ A,
                                                    const float* __restrict__ W,
                                                    const float* __restrict__ bias,
                                                    float* __restrict__ Eo)
{
    __shared__ __align__(16) float As[16][64];
    __shared__ __align__(16) float Bs[16][64];
    const int tid = threadIdx.x;
    const int tx = tid & 15, ty = tid >> 4;
    const int ml = tid >> 2;
    const int kb = (tid & 3) << 2;
    const int m0 = blockIdx.x * 64, n0 = blockIdx.y * 64;
    const int K = Hsz;
    float acc[4][4] = {};
    for (int k0 = 0; k0 < K; k0 += 16) {
        float4 a4 = *(const float4*)(A + (size_t)(m0 + ml) * K + k0 + kb);
        float4 b4 = *(const float4*)(W + (size_t)(n0 + ml) * K + k0 + kb);
        As[kb+0][ml] = a4.x; As[kb+1][ml] = a4.y; As[kb+2][ml] = a4.z; As[kb+3][ml] = a4.w;
        Bs[kb+0][ml] = b4.x; Bs[kb+1][ml] = b4.y; Bs[kb+2][ml] = b4.z; Bs[kb+3][ml] = b4.w;
        __syncthreads();
#pragma unroll
        for (int kk = 0; kk < 16; kk++) {
            float4 av = *(const float4*)(&As[kk][ty << 2]);
            float4 bv = *(const float4*)(&Bs[kk][tx << 2]);
            float a_[4] = {av.x, av.y, av.z, av.w};
            float b_[4] = {bv.x, bv.y, bv.z, bv.w};
#pragma unroll
            for (int i = 0; i < 4; i++)
#pragma unroll
                for (int j = 0; j < 4; j++) acc[i][j] = fmaf(a_[i], b_[j], acc[i][j]);
        }
        __syncthreads();
    }
#pragma unroll
    for (int i = 0; i < 4; i++) {
        int m = m0 + (ty << 2) + i;
        int bb = m & (Bsz - 1);
        int ll = m >> 10;
#pragma unroll
        for (int j = 0; j < 4; j++) {
            int n = n0 + (tx << 2) + j;
            Eo[(size_t)bb * Lsz * Hsz + (size_t)ll * Hsz + n] = acc[i][j] + bias[n];
        }
    }
}

// ============================================================
// LSTM gate GEMM partials: Gp[z][b,j] = (z?h:x)[b,:] . (z?Whh:Wih)[j,:]
// K=256 per half, N=1024.  grid: (16,16,2)
// ============================================================
__global__ __launch_bounds__(256) void gemm_lstm(const float* __restrict__ x,
                                                 const float* __restrict__ hprev,
                                                 const float* __restrict__ Wih,
                                                 const float* __restrict__ Whh,
                                                 float* __restrict__ Gp)
{
    const float* A = blockIdx.z ? hprev : x;
    const float* W = blockIdx.z ? Whh : Wih;
    float* C = Gp + (size_t)blockIdx.z * 1024 * 1024;

    __shared__ __align__(16) float As[16][64];
    __shared__ __align__(16) float Bs[16][64];
    const int tid = threadIdx.x;
    const int tx = tid & 15, ty = tid >> 4;
    const int ml = tid >> 2;
    const int kb = (tid & 3) << 2;
    const int m0 = blockIdx.x * 64, n0 = blockIdx.y * 64;
    const int K = 256;
    float acc[4][4] = {};
    for (int k0 = 0; k0 < K; k0 += 16) {
        float4 a4 = *(const float4*)(A + (size_t)(m0 + ml) * K + k0 + kb);
        float4 b4 = *(const float4*)(W + (size_t)(n0 + ml) * K + k0 + kb);
        As[kb+0][ml] = a4.x; As[kb+1][ml] = a4.y; As[kb+2][ml] = a4.z; As[kb+3][ml] = a4.w;
        Bs[kb+0][ml] = b4.x; Bs[kb+1][ml] = b4.y; Bs[kb+2][ml] = b4.z; Bs[kb+3][ml] = b4.w;
        __syncthreads();
#pragma unroll
        for (int kk = 0; kk < 16; kk++) {
            float4 av = *(const float4*)(&As[kk][ty << 2]);
            float4 bv = *(const float4*)(&Bs[kk][tx << 2]);
            float a_[4] = {av.x, av.y, av.z, av.w};
            float b_[4] = {bv.x, bv.y, bv.z, bv.w};
#pragma unroll
            for (int i = 0; i < 4; i++)
#pragma unroll
                for (int j = 0; j < 4; j++) acc[i][j] = fmaf(a_[i], b_[j], acc[i][j]);
        }
        __syncthreads();
    }
#pragma unroll
    for (int i = 0; i < 4; i++) {
        int m = m0 + (ty << 2) + i;
#pragma unroll
        for (int j = 0; j < 4; j++) {
            int n = n0 + (tx << 2) + j;
            C[(size_t)m * 1024 + n] = acc[i][j];
        }
    }
}

// ============================================================
// generic small GEMM: C[m,n] = A[m,:].W[n,:] + bias[n]
// used for q = h*Wq^T + bq.  grid: (M/64, N/64)
// ============================================================
__global__ __launch_bounds__(256) void gemm_nt(const float* __restrict__ A,
                                               const float* __restrict__ W,
                                               const float* __restrict__ bias,
                                               float* __restrict__ C,
                                               int K, int N)
{
    __shared__ __align__(16) float As[16][64];
    __shared__ __align__(16) float Bs[16][64];
    const int tid = threadIdx.x;
    const int tx = tid & 15, ty = tid >> 4;
    const int ml = tid >> 2;
    const int kb = (tid & 3) << 2;
    const int m0 = blockIdx.x * 64, n0 = blockIdx.y * 64;
    float acc[4][4] = {};
    for (int k0 = 0; k0 < K; k0 += 16) {
        float4 a4 = *(const float4*)(A + (size_t)(m0 + ml) * K + k0 + kb);
        float4 b4 = *(const float4*)(W + (size_t)(n0 + ml) * K + k0 + kb);
        As[kb+0][ml] = a4.x; As[kb+1][ml] = a4.y; As[kb+2][ml] = a4.z; As[kb+3][ml] = a4.w;
        Bs[kb+0][ml] = b4.x; Bs[kb+1][ml] = b4.y; Bs[kb+2][ml] = b4.z; Bs[kb+3][ml] = b4.w;
        __syncthreads();
#pragma unroll
        for (int kk = 0; kk < 16; kk++) {
            float4 av = *(const float4*)(&As[kk][ty << 2]);
            float4 bv = *(const float4*)(&Bs[kk][tx << 2]);
            float a_[4] = {av.x, av.y, av.z, av.w};
            float b_[4] = {bv.x, bv.y, bv.z, bv.w};
#pragma unroll
            for (int i = 0; i < 4; i++)
#pragma unroll
                for (int j = 0; j < 4; j++) acc[i][j] = fmaf(a_[i], b_[j], acc[i][j]);
        }
        __syncthreads();
    }
#pragma unroll
    for (int i = 0; i < 4; i++) {
        int m = m0 + (ty << 2) + i;
#pragma unroll
        for (int j = 0; j < 4; j++) {
            int n = n0 + (tx << 2) + j;
            C[(size_t)m * N + n] = acc[i][j] + bias[n];
        }
    }
}

// ============================================================
// LSTM pointwise gates: torch order i,f,g,o
// grid: 1024 x 256
// ============================================================
__global__ void lstm_gate(const float* __restrict__ Gp,
                          const float* __restrict__ bih, const float* __restrict__ bhh,
                          const float* __restrict__ cin,
                          float* __restrict__ hout, float* __restrict__ cout)
{
    const int b = blockIdx.x, hh = threadIdx.x;
    const float* g0 = Gp + (size_t)b * 1024;
    const float* g1 = Gp + (size_t)1024 * 1024 + (size_t)b * 1024;
    float gi = g0[hh]      + g1[hh]      + bih[hh]      + bhh[hh];
    float gf = g0[256+hh]  + g1[256+hh]  + bih[256+hh]  + bhh[256+hh];
    float gc = g0[512+hh]  + g1[512+hh]  + bih[512+hh]  + bhh[512+hh];
    float go = g0[768+hh]  + g1[768+hh]  + bih[768+hh]  + bhh[768+hh];
    float ii = 1.0f / (1.0f + expf(-gi));
    float ff = 1.0f / (1.0f + expf(-gf));
    float oo = 1.0f / (1.0f + expf(-go));
    float c2 = ff * cin[(size_t)b*Hsz + hh] + ii * tanhf(gc);
    hout[(size_t)b*Hsz + hh] = oo * tanhf(c2);
    cout[(size_t)b*Hsz + hh] = c2;
}

// ============================================================
// fused attention.  one block per batch row, thread = h.
//  PTR=false (glimpse): u -> mask -> softmax -> g_out = sum_l p_l e[b,l,:]
//  PTR=true  (pointer): u -> 10*tanh -> mask -> log_softmax -> write log_p,
//                       argmax (first-index ties) -> write sel (float),
//                       update mask (+ all-true fixup), gather next dec_in
// ============================================================
template<bool PTR>
__global__ __launch_bounds__(256, 4) void attn_kernel(
    const float* __restrict__ q, const float* __restrict__ e,
    const float* __restrict__ v, int* __restrict__ mask,
    float* __restrict__ g_out, float* __restrict__ out, int t,
    float* __restrict__ dec_in, const float* __restrict__ emb)
{
    const int b = blockIdx.x, tid = threadIdx.x;
    const int lane = tid & 63, wid = tid >> 6;
    __shared__ float part[Lsz][4];
    __shared__ float logit_s[Lsz];
    __shared__ float p_s[Lsz];
    __shared__ float scal[2];
    __shared__ int sel_s;

    const float q_h = q[(size_t)b * Hsz + tid];
    const float v_h = v[tid];
    const float* eb = e + (size_t)b * Lsz * Hsz + tid;

    float ereg[Lsz];
    if (!PTR) {
#pragma unroll
        for (int l = 0; l < Lsz; l++) ereg[l] = eb[(size_t)l * Hsz];
    }

#pragma unroll
    for (int l = 0; l < Lsz; l++) {
        float ev = PTR ? eb[(size_t)l * Hsz] : ereg[l];
        float x = tanhf(q_h + ev) * v_h;
#pragma unroll
        for (int o = 32; o > 0; o >>= 1) x += __shfl_xor(x, o, 64);
        if (lane == 0) part[l][wid] = x;
    }
    __syncthreads();

    if (tid < Lsz) {
        float u = part[tid][0] + part[tid][1] + part[tid][2] + part[tid][3];
        float logit = PTR ? 10.0f * tanhf(u) : u;
        if (mask[b * Lsz + tid]) logit = NEGV;
        logit_s[tid] = logit;
    }
    __syncthreads();

    if (tid == 0) {
        float m = logit_s[0];
#pragma unroll
        for (int l = 1; l < Lsz; l++) m = fmaxf(m, logit_s[l]);
        float den = 0.0f;
#pragma unroll
        for (int l = 0; l < Lsz; l++) {
            float pl = expf(logit_s[l] - m);
            p_s[l] = pl;
            den += pl;
        }
        scal[0] = m; scal[1] = den;
        if (PTR) {
            float best = logit_s[0]; int bi = 0;
#pragma unroll
            for (int l = 1; l < Lsz; l++)
                if (logit_s[l] > best) { best = logit_s[l]; bi = l; }
            sel_s = bi;
            out[(size_t)Bsz * Lsz * Lsz + (size_t)b * Lsz + t] = (float)bi;
            mask[b * Lsz + bi] = 1;
            int all = 1;
            for (int l = 0; l < Lsz; l++) all &= mask[b * Lsz + l];
            if (all) mask[b * Lsz + Lsz - 1] = 0;
        }
    }
    __syncthreads();

    if (PTR) {
        const float lse = scal[0] + logf(scal[1]);
        if (tid < Lsz)
            out[(size_t)b * Lsz * Lsz + (size_t)t * Lsz + tid] = logit_s[tid] - lse;
        const int s = sel_s;
        dec_in[(size_t)b * Esz + tid] = emb[(size_t)s * Bsz * Esz + (size_t)b * Esz + tid];
    } else {
        const float inv = 1.0f / scal[1];
        float acc = 0.0f;
#pragma unroll
        for (int l = 0; l < Lsz; l++) acc = fmaf(p_s[l], ereg[l], acc);
        g_out[(size_t)b * Hsz + tid] = acc * inv;
    }
}

// ============================================================
extern "C" void kernel_launch(void* const* d_in, const int* in_sizes, int n_in,
                              void* d_out, int out_size, void* d_ws, size_t ws_size,
                              hipStream_t stream) {
    const float* decoder_input = (const float*)d_in[0];
    const float* emb           = (const float*)d_in[1];   // [L,B,E]
    const float* h0            = (const float*)d_in[2];
    const float* c0            = (const float*)d_in[3];
    const float* context       = (const float*)d_in[4];   // [L,B,H]
    // d_in[5] = init_mask (all false) -- replicated by init_kernel
    const float* Wih    = (const float*)d_in[6];
    const float* Whh    = (const float*)d_in[7];
    const float* bih    = (const float*)d_in[8];
    const float* bhh    = (const float*)d_in[9];
    const float* glWq   = (const float*)d_in[10];
    const float* glbq   = (const float*)d_in[11];
    const float* glWref = (const float*)d_in[12];
    const float* glbref = (const float*)d_in[13];
    const float* glv    = (const float*)d_in[14];
    const float* ptWq   = (const float*)d_in[15];
    const float* ptbq   = (const float*)d_in[16];
    const float* ptWref = (const float*)d_in[17];
    const float* ptbref = (const float*)d_in[18];
    const float* ptv    = (const float*)d_in[19];

    float* out = (float*)d_out;

    // workspace layout (floats)
    float* ws   = (float*)d_ws;
    float* e_gl = ws;                                     // [B,L,H]
    float* e_pt = e_gl + (size_t)Bsz * Lsz * Hsz;         // [B,L,H]
    float* Gp   = e_pt + (size_t)Bsz * Lsz * Hsz;         // 2 x [B,1024]
    float* hb0  = Gp + (size_t)2 * 1024 * 1024;
    float* hb1  = hb0 + (size_t)Bsz * Hsz;
    float* cb0  = hb1 + (size_t)Bsz * Hsz;
    float* cb1  = cb0 + (size_t)Bsz * Hsz;
    float* qb   = cb1 + (size_t)Bsz * Hsz;
    float* gb   = qb  + (size_t)Bsz * Hsz;
    float* dec  = gb  + (size_t)Bsz * Hsz;
    int*   mask = (int*)(dec + (size_t)Bsz * Esz);        // [B,L]

    float* hbuf[2] = {hb0, hb1};
    float* cbuf[2] = {cb0, cb1};

    init_kernel<<<dim3(Bsz), dim3(256), 0, stream>>>(decoder_input, dec, mask);

    dim3 ge(Lsz * Bsz / 64, Hsz / 64);
    eproj_kernel<<<ge, dim3(256), 0, stream>>>(context, glWref, glbref, e_gl);
    eproj_kernel<<<ge, dim3(256), 0, stream>>>(context, ptWref, ptbref, e_pt);

    for (int t = 0; t < Lsz; t++) {
        const float* hin = (t == 0) ? h0 : hbuf[(t + 1) & 1];
        const float* cin = (t == 0) ? c0 : cbuf[(t + 1) & 1];
        float* hout = hbuf[t & 1];
        float* cout = cbuf[t & 1];

        gemm_lstm<<<dim3(16, 16, 2), dim3(256), 0, stream>>>(dec, hin, Wih, Whh, Gp);
        lstm_gate<<<dim3(Bsz), dim3(256), 0, stream>>>(Gp, bih, bhh, cin, hout, cout);

        gemm_nt<<<dim3(16, 4), dim3(256), 0, stream>>>(hout, glWq, glbq, qb, 256, 256);
        attn_kernel<false><<<dim3(Bsz), dim3(256), 0, stream>>>(
            qb, e_gl, glv, mask, gb, nullptr, t, nullptr, nullptr);

        gemm_nt<<<dim3(16, 4), dim3(256), 0, stream>>>(gb, ptWq, ptbq, qb, 256, 256);
        attn_kernel<true><<<dim3(Bsz), dim3(256), 0, stream>>>(
            qb, e_pt, ptv, mask, nullptr, out, t, dec, emb);
    }
}